// Round 1
// baseline (181.171 us; speedup 1.0000x reference)
//
#include <hip/hip_runtime.h>
#include <hip/hip_bf16.h>

typedef unsigned short ushort_t;
typedef __attribute__((ext_vector_type(8))) short bf16x8;
typedef __attribute__((ext_vector_type(4))) float f32x4;

__device__ __forceinline__ ushort_t f2bf(float f) {
    union { float f; unsigned u; } v; v.f = f;
    unsigned r = v.u + 0x7FFF + ((v.u >> 16) & 1);
    return (ushort_t)(r >> 16);
}
__device__ __forceinline__ bf16x8 ld8(const ushort_t* p) { return *(const bf16x8*)p; }

__device__ __forceinline__ unsigned cvt2(float x, float y) {
    __hip_bfloat162 h = __float22bfloat162_rn(make_float2(x, y));
    unsigned r; __builtin_memcpy(&r, &h, 4); return r;
}
__device__ __forceinline__ bf16x8 pack8f(float4 a, float4 b) {
    union { unsigned u[4]; bf16x8 v; } o;
    o.u[0] = cvt2(a.x, a.y); o.u[1] = cvt2(a.z, a.w);
    o.u[2] = cvt2(b.x, b.y); o.u[3] = cvt2(b.z, b.w);
    return o.v;
}

// async global->LDS, 16B per lane; LDS dest = wave-uniform base + lane*16
__device__ __forceinline__ void gload_lds16(const ushort_t* g, ushort_t* l) {
    __builtin_amdgcn_global_load_lds(
        (const __attribute__((address_space(1))) void*)g,
        (__attribute__((address_space(3))) void*)l, 16, 0, 0);
}

// ---------------------------------------------------------------------------
// Fused QKV projection. grid (4, 32, 3) = 384 blocks. 128x128 tile, BK=64,
// pipelined, A and W fp32 (in-register pack to bf16).
// z=0: Q*C1 bf16 [m][n]; z=1: K bf16 [m][n];
// z=2: V^T sigma-permuted bf16 via LDS-transpose epilogue (coalesced stores):
//      dst[((b*8+h)*64+d)*2048 + (s&~127) + 8*(s%16) + ((s>>4)&7)].
// LDS: 2 x 128x72 staging (36.9 KB); z==2 epilogue reuses it as 128x136 lT.
// ---------------------------------------------------------------------------
__global__ __launch_bounds__(256, 2)
void proj_qkv_kernel(const float* __restrict__ Qe, const float* __restrict__ Ke,
                     const float* __restrict__ x,
                     const float* __restrict__ Wq, const float* __restrict__ Wk,
                     const float* __restrict__ Wv,
                     const float* __restrict__ bq, const float* __restrict__ bk,
                     const float* __restrict__ bv,
                     ushort_t* __restrict__ Qo, ushort_t* __restrict__ Ko,
                     ushort_t* __restrict__ Vt)
{
    __shared__ ushort_t smem[2 * 128 * 72];      // lA | lB; reused as lT (128x136)
    ushort_t* lA = smem;
    ushort_t* lB = smem + 128 * 72;

    const int z = blockIdx.z;
    const float* A = (z == 0) ? Qe : (z == 1) ? Ke : x;
    const float* W = (z == 0) ? Wq : (z == 1) ? Wk : Wv;
    const float* bias = (z == 0) ? bq : (z == 1) ? bk : bv;

    const int m0 = blockIdx.y * 128, n0 = blockIdx.x * 128;
    const int t = threadIdx.x;
    const int lane = t & 63, wave = t >> 6;
    const int wm = (wave & 1) * 64, wn = (wave >> 1) * 64;
    const int fr = lane & 15, quad = lane >> 4;

    f32x4 acc[4][4] = {};
    float4 fa[4][2], fw[4][2];

    // prologue: loads for k0 = 0
#pragma unroll
    for (int i = 0; i < 4; ++i) {
        int s = i * 256 + t;
        int r = s >> 3, jp = s & 7;
        const float* pa = A + (size_t)(m0 + r) * 512 + jp * 8;
        fa[i][0] = *(const float4*)pa; fa[i][1] = *(const float4*)(pa + 4);
        const float* pw = W + (size_t)(n0 + r) * 512 + jp * 8;
        fw[i][0] = *(const float4*)pw; fw[i][1] = *(const float4*)(pw + 4);
    }

    for (int kk = 0; kk < 8; ++kk) {
        if (kk) __syncthreads();
#pragma unroll
        for (int i = 0; i < 4; ++i) {
            int s = i * 256 + t;
            int r = s >> 3, jp = s & 7;
            *(bf16x8*)(lA + r * 72 + jp * 8) = pack8f(fa[i][0], fa[i][1]);
            *(bf16x8*)(lB + r * 72 + jp * 8) = pack8f(fw[i][0], fw[i][1]);
        }
        __syncthreads();
        if (kk < 7) {
            int k0 = (kk + 1) * 64;
#pragma unroll
            for (int i = 0; i < 4; ++i) {
                int s = i * 256 + t;
                int r = s >> 3, jp = s & 7;
                const float* pa = A + (size_t)(m0 + r) * 512 + k0 + jp * 8;
                fa[i][0] = *(const float4*)pa; fa[i][1] = *(const float4*)(pa + 4);
                const float* pw = W + (size_t)(n0 + r) * 512 + k0 + jp * 8;
                fw[i][0] = *(const float4*)pw; fw[i][1] = *(const float4*)(pw + 4);
            }
        }

#pragma unroll
        for (int ks = 0; ks < 2; ++ks) {
            bf16x8 af[4], bfrag[4];
#pragma unroll
            for (int mt = 0; mt < 4; ++mt)
                af[mt] = ld8(lA + (wm + mt * 16 + fr) * 72 + (ks * 4 + quad) * 8);
#pragma unroll
            for (int nt = 0; nt < 4; ++nt)
                bfrag[nt] = ld8(lB + (wn + nt * 16 + fr) * 72 + (ks * 4 + quad) * 8);
#pragma unroll
            for (int mt = 0; mt < 4; ++mt)
#pragma unroll
                for (int nt = 0; nt < 4; ++nt)
                    acc[mt][nt] = __builtin_amdgcn_mfma_f32_16x16x32_bf16(
                        af[mt], bfrag[nt], acc[mt][nt], 0, 0, 0);
        }
    }

    const float C1 = 0.125f * 1.44269504088896340736f;
    // C/D: col = lane&15, row = quad*4 + reg (measured m89/m91).
    if (z != 2) {
        ushort_t* dst = (z == 0) ? Qo : Ko;
#pragma unroll
        for (int nt = 0; nt < 4; ++nt) {
            int n = n0 + wn + nt * 16 + fr;
            float bb = bias[n];
#pragma unroll
            for (int mt = 0; mt < 4; ++mt) {
                int mb = m0 + wm + mt * 16 + quad * 4;
                if (z == 0) {
#pragma unroll
                    for (int r = 0; r < 4; ++r)
                        dst[(size_t)(mb + r) * 512 + n] = f2bf((acc[mt][nt][r] + bb) * C1);
                } else {
#pragma unroll
                    for (int r = 0; r < 4; ++r)
                        dst[(size_t)(mb + r) * 512 + n] = f2bf(acc[mt][nt][r] + bb);
                }
            }
        }
    } else {
        // V^T epilogue: sigma-scatter into LDS, then coalesced b128 stores.
        __syncthreads();                  // all waves done reading lA/lB
        ushort_t* lT = smem;              // [n 0..127][sigma-token 0..127], stride 136
#pragma unroll
        for (int nt = 0; nt < 4; ++nt) {
            int nl = wn + nt * 16 + fr;
            float bb = bias[n0 + nl];
#pragma unroll
            for (int mt = 0; mt < 4; ++mt) {
                int tm = wm + mt * 16 + quad * 4;
#pragma unroll
                for (int r = 0; r < 4; ++r) {
                    int tl = tm + r;
                    int sg = 8 * (tl & 15) + ((tl >> 4) & 7);
                    lT[nl * 136 + sg] = f2bf(acc[mt][nt][r] + bb);
                }
            }
        }
        __syncthreads();
        const int bidx = m0 >> 11, m0t = m0 & 2047;
#pragma unroll
        for (int i = 0; i < 8; ++i) {
            int s = i * 256 + t;
            int row = s >> 4, c = s & 15;
            int n = n0 + row;
            int h = n >> 6, d = n & 63;
            bf16x8 v = ld8(lT + row * 136 + c * 8);
            *(bf16x8*)(Vt + ((size_t)((bidx * 8 + h) * 64 + d)) * 2048 + m0t + c * 8) = v;
        }
    }
}

// ---------------------------------------------------------------------------
// O-projection: 64x64 tile, grid (8,64) = 512 blocks (2/CU), BK=64, pipelined.
// A bf16, W fp32 (in-register pack).
// ---------------------------------------------------------------------------
__global__ __launch_bounds__(256, 2)
void gemm_o_kernel(const ushort_t* __restrict__ A, const float* __restrict__ W,
                   const float* __restrict__ bias, float* __restrict__ dst)
{
    __shared__ ushort_t lA[64 * 72];
    __shared__ ushort_t lB[64 * 72];
    const int m0 = blockIdx.y * 64, n0 = blockIdx.x * 64;
    const int t = threadIdx.x;
    const int lane = t & 63, wave = t >> 6;
    const int wm = (wave & 1) * 32, wn = (wave >> 1) * 32;
    const int fr = lane & 15, quad = lane >> 4;

    f32x4 acc[2][2] = {};
    bf16x8 va[2];
    float4 fw[2][2];

#pragma unroll
    for (int i = 0; i < 2; ++i) {
        int s = i * 256 + t;
        int r = s >> 3, jp = s & 7;
        va[i] = ld8(A + (size_t)(m0 + r) * 512 + jp * 8);
        const float* p = W + (size_t)(n0 + r) * 512 + jp * 8;
        fw[i][0] = *(const float4*)p; fw[i][1] = *(const float4*)(p + 4);
    }

    for (int kk = 0; kk < 8; ++kk) {
        if (kk) __syncthreads();
#pragma unroll
        for (int i = 0; i < 2; ++i) {
            int s = i * 256 + t;
            int r = s >> 3, jp = s & 7;
            *(bf16x8*)(lA + r * 72 + jp * 8) = va[i];
            *(bf16x8*)(lB + r * 72 + jp * 8) = pack8f(fw[i][0], fw[i][1]);
        }
        __syncthreads();
        if (kk < 7) {
            int k0 = (kk + 1) * 64;
#pragma unroll
            for (int i = 0; i < 2; ++i) {
                int s = i * 256 + t;
                int r = s >> 3, jp = s & 7;
                va[i] = ld8(A + (size_t)(m0 + r) * 512 + k0 + jp * 8);
                const float* p = W + (size_t)(n0 + r) * 512 + k0 + jp * 8;
                fw[i][0] = *(const float4*)p; fw[i][1] = *(const float4*)(p + 4);
            }
        }

        bf16x8 af[2][2], bfrag[2][2];
#pragma unroll
        for (int ks = 0; ks < 2; ++ks) {
#pragma unroll
            for (int mt = 0; mt < 2; ++mt)
                af[mt][ks] = ld8(lA + (wm + mt * 16 + fr) * 72 + (ks * 4 + quad) * 8);
#pragma unroll
            for (int nt = 0; nt < 2; ++nt)
                bfrag[nt][ks] = ld8(lB + (wn + nt * 16 + fr) * 72 + (ks * 4 + quad) * 8);
        }
#pragma unroll
        for (int ks = 0; ks < 2; ++ks)
#pragma unroll
            for (int mt = 0; mt < 2; ++mt)
#pragma unroll
                for (int nt = 0; nt < 2; ++nt)
                    acc[mt][nt] = __builtin_amdgcn_mfma_f32_16x16x32_bf16(
                        af[mt][ks], bfrag[nt][ks], acc[mt][nt], 0, 0, 0);
    }

#pragma unroll
    for (int nt = 0; nt < 2; ++nt) {
        int n = n0 + wn + nt * 16 + fr;
        float bb = bias[n];
#pragma unroll
        for (int mt = 0; mt < 2; ++mt) {
            int mb = m0 + wm + mt * 16 + quad * 4;
#pragma unroll
            for (int r = 0; r < 4; ++r)
                dst[(size_t)(mb + r) * 512 + n] = acc[mt][nt][r] + bb;
        }
    }
}

// ---------------------------------------------------------------------------
// Single-pass flash attention, v2: 2 waves x 32 q-rows per block (128 thr),
// grid (32,8,2) = 512 blocks = 2 blocks/CU. kb/vb fragments read ONCE and fed
// to two MFMAs (halves per-q K/V LDS traffic). K/V staged with
// global_load_lds width-16 into unpadded, XOR-chunk-swizzled LDS
// (both-sides swizzle: pre-swizzled global source + swizzled ds_read).
// K double-buffered; V staged under QK^T+softmax with counted vmcnt(8) +
// raw s_barrier so next-tile K loads stay in flight across PV.
// LDS: lK 2x16KB + lV 16KB + lP 16KB = 64 KB/block.
// No-max softmax (C1 folded into Q), sigma key order in lP/lV.
// ---------------------------------------------------------------------------
__global__ __launch_bounds__(128, 1)
void attn_kernel(const ushort_t* __restrict__ Q, const ushort_t* __restrict__ K,
                 const ushort_t* __restrict__ Vt, ushort_t* __restrict__ O)
{
    __shared__ ushort_t lK[2 * 128 * 64];   // [buf][key][chunk^ (key&7)], 32 KB
    __shared__ ushort_t lV[64 * 128];       // [d][sigma-chunk ^ (d&7)], 16 KB
    __shared__ ushort_t lP[64 * 128];       // [q][sigma-chunk ^ (q&7)], 16 KB

    const int b = blockIdx.z, h = blockIdx.y;
    const int q0 = blockIdx.x * 64;
    const int t = threadIdx.x;
    const int lane = t & 63, w = t >> 6;
    const int wq = w * 32;
    const int fr = lane & 15, quad = lane >> 4;
    const int fr7 = fr & 7;

    // Q fragments in registers: 2 row-blocks x 2 k-slices
    bf16x8 aq[2][2];
#pragma unroll
    for (int mq = 0; mq < 2; ++mq) {
        const ushort_t* qp = Q + (size_t)(b * 2048 + q0 + wq + mq * 16 + fr) * 512
                               + h * 64 + quad * 8;
        aq[mq][0] = ld8(qp);
        aq[mq][1] = ld8(qp + 32);
    }

    // per-lane pre-swizzled staging source bases (rule #21: swizzle the global
    // source so the linear global_load_lds dest + XOR'd ds_read agree).
    const int krow = w * 8 + (lane >> 3);             // K: 8 rows x 8 chunks / wave instr
    const ushort_t* kbase = K + (size_t)(b * 2048 + krow) * 512 + h * 64
                              + (((lane & 7) ^ (krow & 7)) << 3);
    const int vrow = w * 4 + (lane >> 4);             // V: 4 rows x 16 chunks / wave instr
    const ushort_t* vbase = Vt + (size_t)((b * 8 + h) * 64 + vrow) * 2048
                              + (((lane & 15) ^ (vrow & 7)) << 3);

    // prologue: stage K tile 0 into buffer 0
#pragma unroll
    for (int i = 0; i < 8; ++i)
        gload_lds16(kbase + (size_t)(i * 16) * 512, lK + (i * 16 + w * 8) * 64);
    __syncthreads();                                  // drains vmcnt -> K0 ready

    f32x4 oacc[2][4] = {};
    float lpart[2][4] = {};

    for (int tt = 0; tt < 16; ++tt) {
        const int kv = tt << 7;
        ushort_t* lKc = lK + ((tt & 1) << 13);
        ushort_t* lKn = lK + (((tt & 1) ^ 1) << 13);

        // issue V[tt] (8 loads, oldest) then K[tt+1] (8 loads, youngest)
#pragma unroll
        for (int i = 0; i < 8; ++i)
            gload_lds16(vbase + kv + (size_t)(i * 8) * 2048, lV + (i * 8 + w * 4) * 128);
        if (tt < 15) {
#pragma unroll
            for (int i = 0; i < 8; ++i)
                gload_lds16(kbase + (size_t)(kv + 128 + i * 16) * 512,
                            lKn + (i * 16 + w * 8) * 64);
        }

        // QK^T: each kb read once, feeds both q row-blocks
        f32x4 sc[2][8] = {};
#pragma unroll
        for (int ks = 0; ks < 2; ++ks)
#pragma unroll
            for (int nt = 0; nt < 8; ++nt) {
                bf16x8 kb = ld8(lKc + (nt * 16 + fr) * 64 + (((ks * 4 + quad) ^ fr7) << 3));
                sc[0][nt] = __builtin_amdgcn_mfma_f32_16x16x32_bf16(aq[0][ks], kb, sc[0][nt], 0, 0, 0);
                sc[1][nt] = __builtin_amdgcn_mfma_f32_16x16x32_bf16(aq[1][ks], kb, sc[1][nt], 0, 0, 0);
            }

        // no-max softmax + pack P (sigma order) into swizzled lP (wave-local rows)
#pragma unroll
        for (int mq = 0; mq < 2; ++mq)
#pragma unroll
            for (int r = 0; r < 4; ++r) {
                int row = wq + mq * 16 + quad * 4 + r;
                float pv[8]; float acc = 0.f;
#pragma unroll
                for (int nt = 0; nt < 8; ++nt) { pv[nt] = exp2f(sc[mq][nt][r]); acc += pv[nt]; }
                lpart[mq][r] += acc;
                union { unsigned u[4]; bf16x8 v; } pu;
                pu.u[0] = cvt2(pv[0], pv[1]); pu.u[1] = cvt2(pv[2], pv[3]);
                pu.u[2] = cvt2(pv[4], pv[5]); pu.u[3] = cvt2(pv[6], pv[7]);
                *(bf16x8*)(lP + row * 128 + ((fr ^ (row & 7)) << 3)) = pu.v;
            }

        // V[tt] landed (8 oldest); K[tt+1] stays in flight across PV (T4)
        if (tt < 15) asm volatile("s_waitcnt vmcnt(8)" ::: "memory");
        else         asm volatile("s_waitcnt vmcnt(0)" ::: "memory");
        __builtin_amdgcn_s_barrier();
        __builtin_amdgcn_sched_barrier(0);

        // PV: each vb read once, feeds both q row-blocks
#pragma unroll
        for (int ks = 0; ks < 4; ++ks) {
            int cs = ((ks * 4 + quad) ^ fr7) << 3;
            bf16x8 ap0 = ld8(lP + (wq + fr) * 128 + cs);
            bf16x8 ap1 = ld8(lP + (wq + 16 + fr) * 128 + cs);
#pragma unroll
            for (int nt = 0; nt < 4; ++nt) {
                bf16x8 vb = ld8(lV + (nt * 16 + fr) * 128 + cs);
                oacc[0][nt] = __builtin_amdgcn_mfma_f32_16x16x32_bf16(ap0, vb, oacc[0][nt], 0, 0, 0);
                oacc[1][nt] = __builtin_amdgcn_mfma_f32_16x16x32_bf16(ap1, vb, oacc[1][nt], 0, 0, 0);
            }
        }
        __syncthreads();   // all lV/lKc reads done; drains vmcnt(0) -> K[tt+1] ready
    }

    // epilogue: reduce l across fr lanes, scale, store
#pragma unroll
    for (int mq = 0; mq < 2; ++mq)
#pragma unroll
        for (int r = 0; r < 4; ++r) {
            float rs = lpart[mq][r];
#pragma unroll
            for (int o = 1; o < 16; o <<= 1)
                rs += __shfl_xor(rs, o, 64);
            float inv = 1.f / rs;
            int q = q0 + wq + mq * 16 + quad * 4 + r;
#pragma unroll
            for (int nt = 0; nt < 4; ++nt)
                O[(size_t)(b * 2048 + q) * 512 + h * 64 + nt * 16 + fr] =
                    f2bf(oacc[mq][nt][r] * inv);
        }
}

extern "C" void kernel_launch(void* const* d_in, const int* in_sizes, int n_in,
                              void* d_out, int out_size, void* d_ws, size_t ws_size,
                              hipStream_t stream) {
    const float* x   = (const float*)d_in[0];
    const float* Qe  = (const float*)d_in[1];
    const float* Ke  = (const float*)d_in[2];
    // d_in[3..6] scalars unused (drofe_fn is None in reference)
    const float* Wq  = (const float*)d_in[7];
    const float* bq  = (const float*)d_in[8];
    const float* Wk  = (const float*)d_in[9];
    const float* bk  = (const float*)d_in[10];
    const float* Wv  = (const float*)d_in[11];
    const float* bv  = (const float*)d_in[12];
    const float* Wo  = (const float*)d_in[13];
    const float* bo  = (const float*)d_in[14];

    const size_t NTOK = 2 * 2048;
    const size_t ACT = NTOK * 512;

    ushort_t* p = (ushort_t*)d_ws;
    ushort_t* Qws = p; p += ACT;           // [B,S,512], pre-scaled by C1
    ushort_t* Kws = p; p += ACT;           // [B,S,512]
    ushort_t* Vt  = p; p += ACT;           // [B,H,64,S] sigma-permuted per 128
    ushort_t* Ows = p; p += ACT;           // [B,S,512]

    proj_qkv_kernel<<<dim3(4, 32, 3), 256, 0, stream>>>(Qe, Ke, x, Wq, Wk, Wv,
                                                        bq, bk, bv, Qws, Kws, Vt);
    attn_kernel<<<dim3(32, 8, 2), 128, 0, stream>>>(Qws, Kws, Vt, Ows);
    gemm_o_kernel<<<dim3(8, 64), 256, 0, stream>>>(Ows, Wo, bo, (float*)d_out);
}

// Round 2
// 165.327 us; speedup vs baseline: 1.0958x; 1.0958x over previous
//
#include <hip/hip_runtime.h>
#include <hip/hip_bf16.h>

typedef unsigned short ushort_t;
typedef __attribute__((ext_vector_type(8))) short bf16x8;
typedef __attribute__((ext_vector_type(4))) float f32x4;

__device__ __forceinline__ ushort_t f2bf(float f) {
    union { float f; unsigned u; } v; v.f = f;
    unsigned r = v.u + 0x7FFF + ((v.u >> 16) & 1);
    return (ushort_t)(r >> 16);
}
__device__ __forceinline__ bf16x8 ld8(const ushort_t* p) { return *(const bf16x8*)p; }

__device__ __forceinline__ unsigned cvt2(float x, float y) {
    __hip_bfloat162 h = __float22bfloat162_rn(make_float2(x, y));
    unsigned r; __builtin_memcpy(&r, &h, 4); return r;
}
__device__ __forceinline__ bf16x8 pack8f(float4 a, float4 b) {
    union { unsigned u[4]; bf16x8 v; } o;
    o.u[0] = cvt2(a.x, a.y); o.u[1] = cvt2(a.z, a.w);
    o.u[2] = cvt2(b.x, b.y); o.u[3] = cvt2(b.z, b.w);
    return o.v;
}

// async global->LDS, 16B per lane; LDS dest = wave-uniform base + lane*16
__device__ __forceinline__ void gload_lds16(const ushort_t* g, ushort_t* l) {
    __builtin_amdgcn_global_load_lds(
        (const __attribute__((address_space(1))) void*)g,
        (__attribute__((address_space(3))) void*)l, 16, 0, 0);
}

// ---------------------------------------------------------------------------
// Fused QKV projection. grid (4, 32, 3) = 384 blocks. 128x128 tile, BK=64,
// pipelined, A and W fp32 (in-register pack to bf16).
// z=0: Q*C1 bf16 [m][n]; z=1: K bf16 [m][n];
// z=2: V^T sigma-permuted bf16 via LDS-transpose epilogue (coalesced stores):
//      dst[((b*8+h)*64+d)*2048 + (s&~127) + 8*(s%16) + ((s>>4)&7)].
// LDS: 2 x 128x72 staging (36.9 KB); z==2 epilogue reuses it as 128x136 lT.
// ---------------------------------------------------------------------------
__global__ __launch_bounds__(256, 2)
void proj_qkv_kernel(const float* __restrict__ Qe, const float* __restrict__ Ke,
                     const float* __restrict__ x,
                     const float* __restrict__ Wq, const float* __restrict__ Wk,
                     const float* __restrict__ Wv,
                     const float* __restrict__ bq, const float* __restrict__ bk,
                     const float* __restrict__ bv,
                     ushort_t* __restrict__ Qo, ushort_t* __restrict__ Ko,
                     ushort_t* __restrict__ Vt)
{
    __shared__ ushort_t smem[2 * 128 * 72];      // lA | lB; reused as lT (128x136)
    ushort_t* lA = smem;
    ushort_t* lB = smem + 128 * 72;

    const int z = blockIdx.z;
    const float* A = (z == 0) ? Qe : (z == 1) ? Ke : x;
    const float* W = (z == 0) ? Wq : (z == 1) ? Wk : Wv;
    const float* bias = (z == 0) ? bq : (z == 1) ? bk : bv;

    const int m0 = blockIdx.y * 128, n0 = blockIdx.x * 128;
    const int t = threadIdx.x;
    const int lane = t & 63, wave = t >> 6;
    const int wm = (wave & 1) * 64, wn = (wave >> 1) * 64;
    const int fr = lane & 15, quad = lane >> 4;

    f32x4 acc[4][4] = {};
    float4 fa[4][2], fw[4][2];

    // prologue: loads for k0 = 0
#pragma unroll
    for (int i = 0; i < 4; ++i) {
        int s = i * 256 + t;
        int r = s >> 3, jp = s & 7;
        const float* pa = A + (size_t)(m0 + r) * 512 + jp * 8;
        fa[i][0] = *(const float4*)pa; fa[i][1] = *(const float4*)(pa + 4);
        const float* pw = W + (size_t)(n0 + r) * 512 + jp * 8;
        fw[i][0] = *(const float4*)pw; fw[i][1] = *(const float4*)(pw + 4);
    }

    for (int kk = 0; kk < 8; ++kk) {
        if (kk) __syncthreads();
#pragma unroll
        for (int i = 0; i < 4; ++i) {
            int s = i * 256 + t;
            int r = s >> 3, jp = s & 7;
            *(bf16x8*)(lA + r * 72 + jp * 8) = pack8f(fa[i][0], fa[i][1]);
            *(bf16x8*)(lB + r * 72 + jp * 8) = pack8f(fw[i][0], fw[i][1]);
        }
        __syncthreads();
        if (kk < 7) {
            int k0 = (kk + 1) * 64;
#pragma unroll
            for (int i = 0; i < 4; ++i) {
                int s = i * 256 + t;
                int r = s >> 3, jp = s & 7;
                const float* pa = A + (size_t)(m0 + r) * 512 + k0 + jp * 8;
                fa[i][0] = *(const float4*)pa; fa[i][1] = *(const float4*)(pa + 4);
                const float* pw = W + (size_t)(n0 + r) * 512 + k0 + jp * 8;
                fw[i][0] = *(const float4*)pw; fw[i][1] = *(const float4*)(pw + 4);
            }
        }

#pragma unroll
        for (int ks = 0; ks < 2; ++ks) {
            bf16x8 af[4], bfrag[4];
#pragma unroll
            for (int mt = 0; mt < 4; ++mt)
                af[mt] = ld8(lA + (wm + mt * 16 + fr) * 72 + (ks * 4 + quad) * 8);
#pragma unroll
            for (int nt = 0; nt < 4; ++nt)
                bfrag[nt] = ld8(lB + (wn + nt * 16 + fr) * 72 + (ks * 4 + quad) * 8);
#pragma unroll
            for (int mt = 0; mt < 4; ++mt)
#pragma unroll
                for (int nt = 0; nt < 4; ++nt)
                    acc[mt][nt] = __builtin_amdgcn_mfma_f32_16x16x32_bf16(
                        af[mt], bfrag[nt], acc[mt][nt], 0, 0, 0);
        }
    }

    const float C1 = 0.125f * 1.44269504088896340736f;
    // C/D: col = lane&15, row = quad*4 + reg (measured m89/m91).
    if (z != 2) {
        ushort_t* dst = (z == 0) ? Qo : Ko;
#pragma unroll
        for (int nt = 0; nt < 4; ++nt) {
            int n = n0 + wn + nt * 16 + fr;
            float bb = bias[n];
#pragma unroll
            for (int mt = 0; mt < 4; ++mt) {
                int mb = m0 + wm + mt * 16 + quad * 4;
                if (z == 0) {
#pragma unroll
                    for (int r = 0; r < 4; ++r)
                        dst[(size_t)(mb + r) * 512 + n] = f2bf((acc[mt][nt][r] + bb) * C1);
                } else {
#pragma unroll
                    for (int r = 0; r < 4; ++r)
                        dst[(size_t)(mb + r) * 512 + n] = f2bf(acc[mt][nt][r] + bb);
                }
            }
        }
    } else {
        // V^T epilogue: sigma-scatter into LDS, then coalesced b128 stores.
        __syncthreads();                  // all waves done reading lA/lB
        ushort_t* lT = smem;              // [n 0..127][sigma-token 0..127], stride 136
#pragma unroll
        for (int nt = 0; nt < 4; ++nt) {
            int nl = wn + nt * 16 + fr;
            float bb = bias[n0 + nl];
#pragma unroll
            for (int mt = 0; mt < 4; ++mt) {
                int tm = wm + mt * 16 + quad * 4;
#pragma unroll
                for (int r = 0; r < 4; ++r) {
                    int tl = tm + r;
                    int sg = 8 * (tl & 15) + ((tl >> 4) & 7);
                    lT[nl * 136 + sg] = f2bf(acc[mt][nt][r] + bb);
                }
            }
        }
        __syncthreads();
        const int bidx = m0 >> 11, m0t = m0 & 2047;
#pragma unroll
        for (int i = 0; i < 8; ++i) {
            int s = i * 256 + t;
            int row = s >> 4, c = s & 15;
            int n = n0 + row;
            int h = n >> 6, d = n & 63;
            bf16x8 v = ld8(lT + row * 136 + c * 8);
            *(bf16x8*)(Vt + ((size_t)((bidx * 8 + h) * 64 + d)) * 2048 + m0t + c * 8) = v;
        }
    }
}

// ---------------------------------------------------------------------------
// O-projection: 64x64 tile, grid (8,64) = 512 blocks (2/CU), BK=64, pipelined.
// A bf16, W fp32 (in-register pack).
// ---------------------------------------------------------------------------
__global__ __launch_bounds__(256, 2)
void gemm_o_kernel(const ushort_t* __restrict__ A, const float* __restrict__ W,
                   const float* __restrict__ bias, float* __restrict__ dst)
{
    __shared__ ushort_t lA[64 * 72];
    __shared__ ushort_t lB[64 * 72];
    const int m0 = blockIdx.y * 64, n0 = blockIdx.x * 64;
    const int t = threadIdx.x;
    const int lane = t & 63, wave = t >> 6;
    const int wm = (wave & 1) * 32, wn = (wave >> 1) * 32;
    const int fr = lane & 15, quad = lane >> 4;

    f32x4 acc[2][2] = {};
    bf16x8 va[2];
    float4 fw[2][2];

#pragma unroll
    for (int i = 0; i < 2; ++i) {
        int s = i * 256 + t;
        int r = s >> 3, jp = s & 7;
        va[i] = ld8(A + (size_t)(m0 + r) * 512 + jp * 8);
        const float* p = W + (size_t)(n0 + r) * 512 + jp * 8;
        fw[i][0] = *(const float4*)p; fw[i][1] = *(const float4*)(p + 4);
    }

    for (int kk = 0; kk < 8; ++kk) {
        if (kk) __syncthreads();
#pragma unroll
        for (int i = 0; i < 2; ++i) {
            int s = i * 256 + t;
            int r = s >> 3, jp = s & 7;
            *(bf16x8*)(lA + r * 72 + jp * 8) = va[i];
            *(bf16x8*)(lB + r * 72 + jp * 8) = pack8f(fw[i][0], fw[i][1]);
        }
        __syncthreads();
        if (kk < 7) {
            int k0 = (kk + 1) * 64;
#pragma unroll
            for (int i = 0; i < 2; ++i) {
                int s = i * 256 + t;
                int r = s >> 3, jp = s & 7;
                va[i] = ld8(A + (size_t)(m0 + r) * 512 + k0 + jp * 8);
                const float* p = W + (size_t)(n0 + r) * 512 + k0 + jp * 8;
                fw[i][0] = *(const float4*)p; fw[i][1] = *(const float4*)(p + 4);
            }
        }

        bf16x8 af[2][2], bfrag[2][2];
#pragma unroll
        for (int ks = 0; ks < 2; ++ks) {
#pragma unroll
            for (int mt = 0; mt < 2; ++mt)
                af[mt][ks] = ld8(lA + (wm + mt * 16 + fr) * 72 + (ks * 4 + quad) * 8);
#pragma unroll
            for (int nt = 0; nt < 2; ++nt)
                bfrag[nt][ks] = ld8(lB + (wn + nt * 16 + fr) * 72 + (ks * 4 + quad) * 8);
        }
#pragma unroll
        for (int ks = 0; ks < 2; ++ks)
#pragma unroll
            for (int mt = 0; mt < 2; ++mt)
#pragma unroll
                for (int nt = 0; nt < 2; ++nt)
                    acc[mt][nt] = __builtin_amdgcn_mfma_f32_16x16x32_bf16(
                        af[mt][ks], bfrag[nt][ks], acc[mt][nt], 0, 0, 0);
    }

#pragma unroll
    for (int nt = 0; nt < 2; ++nt) {
        int n = n0 + wn + nt * 16 + fr;
        float bb = bias[n];
#pragma unroll
        for (int mt = 0; mt < 2; ++mt) {
            int mb = m0 + wm + mt * 16 + quad * 4;
#pragma unroll
            for (int r = 0; r < 4; ++r)
                dst[(size_t)(mb + r) * 512 + n] = acc[mt][nt][r] + bb;
        }
    }
}

// ---------------------------------------------------------------------------
// Single-pass flash attention, v3: v1 shape (4 waves x 16 q-rows, 256 thr,
// grid (32,8,2)=512 blocks = 2 blocks/CU = 8 waves/CU) + v2's verified
// global_load_lds staging with XOR chunk-swizzle (both-sides: pre-swizzled
// global source, swizzled ds_read) and counted-vmcnt K prefetch.
// Removes the 8-way-conflicting reg-staged ds_writes (v1's main conflict
// source) while keeping v1's latency-hiding occupancy.
// LDS: lK 2x16KB (dbuf) + lV 16KB + lP 16KB = 64 KB -> 2 blocks/CU.
// No-max softmax (C1 folded into Q), sigma key order in lP/lV.
// ---------------------------------------------------------------------------
__global__ __launch_bounds__(256, 2)
void attn_kernel(const ushort_t* __restrict__ Q, const ushort_t* __restrict__ K,
                 const ushort_t* __restrict__ Vt, ushort_t* __restrict__ O)
{
    __shared__ ushort_t lK[2 * 128 * 64];   // [buf][key][slot], LDS[key][s]=chunk s^(key&7)
    __shared__ ushort_t lV[64 * 128];       // [d][slot16], LDS[d][s]=chunk s^(d&7)
    __shared__ ushort_t lP[64 * 128];       // [q][slot16], LDS[q][s]=chunk s^(q&7); wave-local

    const int b = blockIdx.z, h = blockIdx.y;
    const int q0 = blockIdx.x * 64;
    const int t = threadIdx.x;
    const int lane = t & 63, w = t >> 6;
    const int wq = w * 16;
    const int fr = lane & 15, quad = lane >> 4;
    const int fr7 = fr & 7;

    // Q fragments in registers
    bf16x8 aq[2];
    {
        const ushort_t* qp = Q + (size_t)(b * 2048 + q0 + wq + fr) * 512 + h * 64 + quad * 8;
        aq[0] = ld8(qp);
        aq[1] = ld8(qp + 32);
    }

    // staging bases: pre-swizzled global source chunks (rule #21), linear LDS dest.
    // K: wave w stages keys [w*32, w*32+32) in 4 instrs of 8 keys each.
    const int krl = lane >> 3;                        // key sub-row 0..7
    const ushort_t* kbase = K + (size_t)(b * 2048 + w * 32 + krl) * 512 + h * 64
                              + (((lane & 7) ^ (krl & 7)) << 3);
    // V: wave w stages d-rows {i*16 + w*4 + (lane>>4)}, 4 instrs of 4 rows each.
    const int vrl = w * 4 + (lane >> 4);              // d&7 lane-constant (i*16 == 0 mod 8)
    const ushort_t* vbase = Vt + (size_t)((b * 8 + h) * 64 + vrl) * 2048
                              + (((lane & 15) ^ (vrl & 7)) << 3);

    // prologue: stage K tile 0 into buffer 0
#pragma unroll
    for (int i = 0; i < 4; ++i)
        gload_lds16(kbase + (size_t)(i * 8) * 512, lK + (w * 32 + i * 8) * 64);
    __syncthreads();                                  // drains vmcnt -> K0 ready

    f32x4 oacc[4] = {};
    float lpart[4] = {};

    for (int tt = 0; tt < 16; ++tt) {
        const int kv = tt << 7;
        ushort_t* lKc = lK + ((tt & 1) << 13);
        ushort_t* lKn = lK + (((tt & 1) ^ 1) << 13);

        // issue V[tt] (4 loads, oldest) then K[tt+1] (4 loads, youngest)
#pragma unroll
        for (int i = 0; i < 4; ++i)
            gload_lds16(vbase + kv + (size_t)(i * 16) * 2048, lV + (i * 16 + w * 4) * 128);
        if (tt < 15) {
#pragma unroll
            for (int i = 0; i < 4; ++i)
                gload_lds16(kbase + (size_t)(kv + 128 + i * 8) * 512,
                            lKn + (w * 32 + i * 8) * 64);
        }

        // QK^T on current K buffer
        f32x4 sc[8] = {};
#pragma unroll
        for (int ks = 0; ks < 2; ++ks)
#pragma unroll
            for (int nt = 0; nt < 8; ++nt) {
                bf16x8 kb = ld8(lKc + (nt * 16 + fr) * 64 + (((ks * 4 + quad) ^ fr7) << 3));
                sc[nt] = __builtin_amdgcn_mfma_f32_16x16x32_bf16(aq[ks], kb, sc[nt], 0, 0, 0);
            }

        // no-max softmax + pack P (sigma order) into swizzled lP (wave-local rows)
#pragma unroll
        for (int r = 0; r < 4; ++r) {
            int row = wq + quad * 4 + r;
            float pv[8]; float acc = 0.f;
#pragma unroll
            for (int nt = 0; nt < 8; ++nt) { pv[nt] = exp2f(sc[nt][r]); acc += pv[nt]; }
            lpart[r] += acc;
            union { unsigned u[4]; bf16x8 v; } pu;
            pu.u[0] = cvt2(pv[0], pv[1]); pu.u[1] = cvt2(pv[2], pv[3]);
            pu.u[2] = cvt2(pv[4], pv[5]); pu.u[3] = cvt2(pv[6], pv[7]);
            *(bf16x8*)(lP + row * 128 + ((fr ^ (row & 7)) << 3)) = pu.v;
        }

        // V[tt] landed (4 oldest); K[tt+1] stays in flight across PV (T4)
        if (tt < 15) asm volatile("s_waitcnt vmcnt(4)" ::: "memory");
        else         asm volatile("s_waitcnt vmcnt(0)" ::: "memory");
        __builtin_amdgcn_s_barrier();
        __builtin_amdgcn_sched_barrier(0);

        // PV
#pragma unroll
        for (int ks = 0; ks < 4; ++ks) {
            int cs = ((ks * 4 + quad) ^ fr7) << 3;
            bf16x8 ap = ld8(lP + (wq + fr) * 128 + cs);
#pragma unroll
            for (int nt = 0; nt < 4; ++nt) {
                bf16x8 vb = ld8(lV + (nt * 16 + fr) * 128 + cs);
                oacc[nt] = __builtin_amdgcn_mfma_f32_16x16x32_bf16(ap, vb, oacc[nt], 0, 0, 0);
            }
        }
        __syncthreads();   // all lV/lKc reads done; drains vmcnt(0) -> K[tt+1] ready
    }

    // epilogue: reduce l across fr lanes, scale, store
#pragma unroll
    for (int r = 0; r < 4; ++r) {
        float rs = lpart[r];
#pragma unroll
        for (int o = 1; o < 16; o <<= 1)
            rs += __shfl_xor(rs, o, 64);
        float inv = 1.f / rs;
        int q = q0 + wq + quad * 4 + r;
#pragma unroll
        for (int nt = 0; nt < 4; ++nt) {
            int d = nt * 16 + fr;
            O[(size_t)(b * 2048 + q) * 512 + h * 64 + d] = f2bf(oacc[nt][r] * inv);
        }
    }
}

extern "C" void kernel_launch(void* const* d_in, const int* in_sizes, int n_in,
                              void* d_out, int out_size, void* d_ws, size_t ws_size,
                              hipStream_t stream) {
    const float* x   = (const float*)d_in[0];
    const float* Qe  = (const float*)d_in[1];
    const float* Ke  = (const float*)d_in[2];
    // d_in[3..6] scalars unused (drofe_fn is None in reference)
    const float* Wq  = (const float*)d_in[7];
    const float* bq  = (const float*)d_in[8];
    const float* Wk  = (const float*)d_in[9];
    const float* bk  = (const float*)d_in[10];
    const float* Wv  = (const float*)d_in[11];
    const float* bv  = (const float*)d_in[12];
    const float* Wo  = (const float*)d_in[13];
    const float* bo  = (const float*)d_in[14];

    const size_t NTOK = 2 * 2048;
    const size_t ACT = NTOK * 512;

    ushort_t* p = (ushort_t*)d_ws;
    ushort_t* Qws = p; p += ACT;           // [B,S,512], pre-scaled by C1
    ushort_t* Kws = p; p += ACT;           // [B,S,512]
    ushort_t* Vt  = p; p += ACT;           // [B,H,64,S] sigma-permuted per 128
    ushort_t* Ows = p; p += ACT;           // [B,S,512]

    proj_qkv_kernel<<<dim3(4, 32, 3), 256, 0, stream>>>(Qe, Ke, x, Wq, Wk, Wv,
                                                        bq, bk, bv, Qws, Kws, Vt);
    attn_kernel<<<dim3(32, 8, 2), 256, 0, stream>>>(Qws, Kws, Vt, Ows);
    gemm_o_kernel<<<dim3(8, 64), 256, 0, stream>>>(Ows, Wo, bo, (float*)d_out);
}